// Round 5
// baseline (12342.456 us; speedup 1.0000x reference)
//
#include <hip/hip_runtime.h>

#define BATCH 8192
#define DM 768
#define NF 12288
#define K_TOP 64
#define RPB 16          // rows per block
#define FCH 128         // features per chunk
#define KT 32           // k tile
#define AS 33           // A LDS stride (floats)
#define BS 33           // B LDS stride (floats)
#define ZBS 128         // zb stride (doubles; merge is serial, conflicts n/a)

typedef unsigned short u16;
typedef unsigned int u32;

// ---------------------------------------------------------------------------
// Encode GEMM (fp32 in, f64 accumulate) + per-row EXACT top-64.
// fp32 x fp32 products are exact in f64; 768-term f64 sums carry ~1e-14
// error vs truth while rank-64/65 z-gaps are ~3e-3 -> selection matches an
// f64 numpy reference with overwhelming probability (no boundary swaps,
// which caused R3's 0.18 absmax).
// 512 blocks x 256 threads; block = 16 rows; 96 chunks of 128 features.
// Thread tile: 4 rows x 2 features (8 f64 FMA per 6 LDS reads -> VALU-bound).
// ---------------------------------------------------------------------------
__global__ __launch_bounds__(256) void encode_topk(
    const float* __restrict__ x, const float* __restrict__ pb,
    const float* __restrict__ we, const float* __restrict__ be,
    float* __restrict__ ov, int* __restrict__ oi)
{
    __shared__ float  A[RPB * AS];       //  2,112 B (centered x tile)
    __shared__ float  B[FCH * BS];       // 16,896 B (W_enc tile)
    __shared__ double zb[RPB * ZBS];     // 16,384 B (exact z chunk)
    __shared__ double tv[RPB * 64];      //  8,192 B (heap values)
    __shared__ u16    ti[RPB * 64];      //  2,048 B (heap indices)
    __shared__ double cmin[RPB];
    __shared__ int    mpos[RPB];

    const int t = threadIdx.x;
    const int rowT = t >> 6;             // 0..3  -> rows rowT*4 .. +3
    const int fT   = t & 63;             // 0..63 -> feats fT*2, fT*2+1
    const int row0 = blockIdx.x * RPB;

    if (t < RPB) { cmin[t] = -__builtin_inf(); mpos[t] = 0; }
    for (int e = t; e < RPB * 64; e += 256) { tv[e] = -__builtin_inf(); ti[e] = 0; }
    __syncthreads();

    #pragma unroll 1
    for (int chunk = 0; chunk < 96; ++chunk) {
        const int f0 = chunk * FCH;
        double acc[4][2];
        #pragma unroll
        for (int i = 0; i < 4; ++i) { acc[i][0] = 0.0; acc[i][1] = 0.0; }

        #pragma unroll 1
        for (int ks = 0; ks < 24; ++ks) {
            __syncthreads();
            {   // stage A: 16 rows x 32 k centered x (2 floats/thread)
                const int r = t >> 4, kk = (t & 15) * 2;
                const size_t g = (size_t)(row0 + r) * DM + ks * KT + kk;
                A[r * AS + kk]     = x[g]     - pb[ks * KT + kk];
                A[r * AS + kk + 1] = x[g + 1] - pb[ks * KT + kk + 1];
            }
            {   // stage B: 128 feats x 32 k of W_enc (16 floats/thread)
                const int f = t >> 1, k0 = (t & 1) * 16;
                const size_t g = (size_t)(f0 + f) * DM + ks * KT + k0;
                #pragma unroll
                for (int j = 0; j < 16; ++j) B[f * BS + k0 + j] = we[g + j];
            }
            __syncthreads();
            #pragma unroll 4
            for (int k = 0; k < KT; ++k) {
                const double b0 = (double)B[(fT * 2)     * BS + k];  // 4-way alias: free-ish
                const double b1 = (double)B[(fT * 2 + 1) * BS + k];
                #pragma unroll
                for (int i = 0; i < 4; ++i) {
                    const double av = (double)A[(rowT * 4 + i) * AS + k];  // broadcast
                    acc[i][0] += av * b0;
                    acc[i][1] += av * b1;
                }
            }
        }

        const double be0 = (double)be[f0 + fT * 2];
        const double be1 = (double)be[f0 + fT * 2 + 1];
        #pragma unroll
        for (int i = 0; i < 4; ++i) {
            zb[(rowT * 4 + i) * ZBS + fT * 2]     = acc[i][0] + be0;
            zb[(rowT * 4 + i) * ZBS + fT * 2 + 1] = acc[i][1] + be1;
        }
        __syncthreads();

        // serial replace-min top-64 merge on EXACT f64, one thread per row.
        // strict >: earliest feature index wins ties (matches stable topk).
        if (t < RPB) {
            double cm = cmin[t]; int mp = mpos[t];
            for (int j = 0; j < FCH; ++j) {
                const double v = zb[t * ZBS + j];
                if (v > cm) {
                    tv[t * 64 + mp] = v; ti[t * 64 + mp] = (u16)(f0 + j);
                    cm = tv[t * 64]; mp = 0;
                    for (int u = 1; u < 64; ++u) {
                        const double w = tv[t * 64 + u];
                        if (w < cm) { cm = w; mp = u; }
                    }
                }
            }
            cmin[t] = cm; mpos[t] = mp;
        }
        __syncthreads();
    }

    for (int e = t; e < RPB * 64; e += 256) {
        const int row = e >> 6, k = e & 63;
        ov[(size_t)(row0 + row) * K_TOP + k] = (float)tv[e];
        oi[(size_t)(row0 + row) * K_TOP + k] = (int)ti[e];
    }
}

// ---------------------------------------------------------------------------
// W_dec [768, 12288] -> W_decT [12288, 768] fp32, 64x64 LDS tiles
// ---------------------------------------------------------------------------
__global__ __launch_bounds__(256) void transpose_wdec(
    const float* __restrict__ wd, float* __restrict__ wdt)
{
    __shared__ float tile[64 * 65];
    const int t = threadIdx.x;
    const int bd = blockIdx.x % 12;
    const int bf = blockIdx.x / 12;
    const int d0 = bd * 64, f0 = bf * 64;
    #pragma unroll
    for (int i = 0; i < 16; ++i) {
        const int idx = t + 256 * i;
        const int dr = idx >> 6, fc = idx & 63;
        tile[dr * 65 + fc] = wd[(size_t)(d0 + dr) * NF + f0 + fc];
    }
    __syncthreads();
    #pragma unroll
    for (int i = 0; i < 16; ++i) {
        const int idx = t + 256 * i;
        const int fr = idx >> 6, dc = idx & 63;
        wdt[(size_t)(f0 + fr) * DM + d0 + dc] = tile[dc * 65 + fr];
    }
}

// ---------------------------------------------------------------------------
// Decode: one block per row. Zeros the row's sparse region, scatters
// relu(topk), computes x_hat. Covers the entire output (no memset needed;
// robust to 0xAA re-poisoning).
// ---------------------------------------------------------------------------
__global__ __launch_bounds__(256) void decode_scatter(
    const float* __restrict__ ov, const int* __restrict__ oi,
    const float* __restrict__ wdt, int use_wdt,
    const float* __restrict__ wd, const float* __restrict__ pb,
    float* __restrict__ out)
{
    const int row = blockIdx.x, t = threadIdx.x;
    __shared__ float sv[K_TOP];
    __shared__ int   si[K_TOP];
    if (t < K_TOP) {
        float v = ov[(size_t)row * K_TOP + t];
        v = v > 0.f ? v : 0.f;
        int ix = oi[(size_t)row * K_TOP + t];
        ix = ix < 0 ? 0 : (ix >= NF ? NF - 1 : ix);   // fault-safety clamp
        sv[t] = v; si[t] = ix;
    }
    float* srow = out + (size_t)BATCH * DM + (size_t)row * NF;
    for (int i = t; i < NF; i += 256) srow[i] = 0.f;   // zero sparse row
    __syncthreads();
    if (t < K_TOP) srow[si[t]] = sv[t];                // scatter relu(topk)
    float a0 = 0.f, a1 = 0.f, a2 = 0.f;
    for (int k = 0; k < K_TOP; ++k) {
        const float v = sv[k];
        if (v <= 0.f) continue;                        // wave-uniform
        if (use_wdt) {
            const float* wr = wdt + (size_t)si[k] * DM;
            a0 += v * wr[t]; a1 += v * wr[t + 256]; a2 += v * wr[t + 512];
        } else {
            a0 += v * wd[(size_t)(t)       * NF + si[k]];
            a1 += v * wd[(size_t)(t + 256) * NF + si[k]];
            a2 += v * wd[(size_t)(t + 512) * NF + si[k]];
        }
    }
    out[(size_t)row * DM + t]       = a0 + pb[t];
    out[(size_t)row * DM + t + 256] = a1 + pb[t + 256];
    out[(size_t)row * DM + t + 512] = a2 + pb[t + 512];
}

extern "C" void kernel_launch(void* const* d_in, const int* in_sizes, int n_in,
                              void* d_out, int out_size, void* d_ws, size_t ws_size,
                              hipStream_t stream) {
    const float* x  = (const float*)d_in[0];
    const float* pb = (const float*)d_in[1];
    const float* we = (const float*)d_in[2];
    const float* be = (const float*)d_in[3];
    const float* wd = (const float*)d_in[4];
    float* out = (float*)d_out;

    // ws: ov 2MB | oi 2MB | W_decT fp32 37.75MB
    const size_t OV = 0;
    const size_t OI = (size_t)BATCH * K_TOP * 4;
    const size_t WT = OI + (size_t)BATCH * K_TOP * 4;
    const size_t need = WT + (size_t)NF * DM * 4;
    float* ov  = (float*)((char*)d_ws + OV);
    int*   oi  = (int*)((char*)d_ws + OI);
    float* wdt = (float*)((char*)d_ws + WT);
    const int use_wdt = (ws_size >= need) ? 1 : 0;

    if (use_wdt)
        hipLaunchKernelGGL(transpose_wdec, dim3(2304), dim3(256), 0, stream, wd, wdt);
    hipLaunchKernelGGL(encode_topk, dim3(512), dim3(256), 0, stream,
                       x, pb, we, be, ov, oi);
    hipLaunchKernelGGL(decode_scatter, dim3(BATCH), dim3(256), 0, stream,
                       ov, oi, wdt, use_wdt, wd, pb, out);
}

// Round 6
// 3274.562 us; speedup vs baseline: 3.7692x; 3.7692x over previous
//
#include <hip/hip_runtime.h>

#define BATCH 8192
#define DM 768
#define NF 12288
#define K_TOP 64
#define KH 96           // candidate heap per row
#define RPB 32          // rows per encode block
#define QCAP 48         // candidate queue capacity
#define HS 97           // heap LDS stride (97%32=1 -> conflict-free across rows)
#define QS 49           // queue LDS stride (49 coprime 32)
#define GS 13           // group-min stride (12 groups of 8)

typedef unsigned short u16;
typedef unsigned int u32;
typedef short bf16x8 __attribute__((ext_vector_type(8)));
typedef float f32x4 __attribute__((ext_vector_type(4)));

union U8 { uint4 q; bf16x8 v; u16 u[8]; };

__device__ __forceinline__ u16 f2b(float f) {   // fp32 -> bf16 RTNE
    u32 i; __builtin_memcpy(&i, &f, 4);
    u32 r = (i + 0x7FFFu + ((i >> 16) & 1u)) >> 16; return (u16)r;
}

// ---------------------------------------------------------------------------
// Encode: bf16 MFMA GEMM on-the-fly converted from fp32, streaming top-96
// per row on approximate z~. |z~ - z| sigma ~ 0.0023; heap-96 margin
// (z~64 - z~96 ~ 0.095 ~ 40 sigma) guarantees exact top-64 is inside.
// 256 blocks x 256 threads; 32 rows/block; 96 chunks of 128 feats; K-tile 64.
// ---------------------------------------------------------------------------
__global__ __launch_bounds__(256) void encode_topk(
    const float* __restrict__ x, const float* __restrict__ pb,
    const float* __restrict__ we, const float* __restrict__ be,
    float* __restrict__ candv, int* __restrict__ candi)
{
    __shared__ u16   Au[RPB * 72];      //  4,608 B  A tile bf16 (32 x 64)
    __shared__ u16   Bu[128 * 72];      // 18,432 B  B tile bf16 (128 x 64)
    __shared__ float hv[RPB * HS];      // 12,416 B  heap values (96 used)
    __shared__ u16   hidx[RPB * HS];    //  6,208 B  heap indices
    __shared__ float gmin[RPB * GS];    //  1,664 B  per-group (of 8) minima
    __shared__ float qv[RPB * QS];      //  6,272 B  queue values
    __shared__ int   qi[RPB * QS];      //  6,272 B  queue indices
    __shared__ float pbl[DM];           //  3,072 B  pre_bias
    __shared__ float cminA[RPB];
    __shared__ int   cposA[RPB];
    __shared__ int   qn[RPB];

    const int t = threadIdx.x;
    const int w = t >> 6, l = t & 63, g = l >> 4, ln = l & 15;
    const int row0 = blockIdx.x * RPB;

    if (t < RPB) { cminA[t] = -__builtin_inff(); cposA[t] = 0; qn[t] = 0; }
    for (int e = t; e < RPB * HS; e += 256) { hv[e] = -__builtin_inff(); hidx[e] = 0; }
    for (int e = t; e < RPB * GS; e += 256) gmin[e] = -__builtin_inff();
    for (int e = t; e < DM; e += 256) pbl[e] = pb[e];

    const float4* x4  = (const float4*)x;
    const float4* we4 = (const float4*)we;
    const int ar = t >> 3, akq = t & 7;      // A stager: row, k-octet
    const int bf_ = t >> 1, bkh = t & 1;     // B stager: feat, k-half(32)

    float4 pa[2], pw[8];                      // prefetch registers
    {   // prologue: (chunk 0, ks 0)
        const size_t ga = ((size_t)(row0 + ar) * DM + akq * 8) >> 2;
        pa[0] = x4[ga]; pa[1] = x4[ga + 1];
        const size_t gb = ((size_t)bf_ * DM + bkh * 32) >> 2;
        #pragma unroll
        for (int i = 0; i < 8; ++i) pw[i] = we4[gb + i];
    }
    __syncthreads();

    #pragma unroll 1
    for (int chunk = 0; chunk < 96; ++chunk) {
        const int f0 = chunk * 128;
        f32x4 acc[2][2];
        #pragma unroll
        for (int i = 0; i < 2; ++i)
            #pragma unroll
            for (int j = 0; j < 2; ++j) acc[i][j] = (f32x4){0,0,0,0};

        #pragma unroll 1
        for (int ks = 0; ks < 12; ++ks) {
            __syncthreads();
            {   // store A prefetch -> LDS (centered, bf16)
                U8 o;
                #pragma unroll
                for (int j = 0; j < 8; ++j)
                    o.u[j] = f2b(((const float*)pa)[j] - pbl[ks * 64 + akq * 8 + j]);
                *(uint4*)&Au[ar * 72 + akq * 8] = o.q;
            }
            {   // store B prefetch -> LDS (bf16)
                #pragma unroll
                for (int h = 0; h < 4; ++h) {
                    U8 o;
                    #pragma unroll
                    for (int j = 0; j < 8; ++j)
                        o.u[j] = f2b(((const float*)pw)[h * 8 + j]);
                    *(uint4*)&Bu[bf_ * 72 + bkh * 32 + h * 8] = o.q;
                }
            }
            __syncthreads();
            const int ns = chunk * 12 + ks + 1;   // prefetch next tiles
            if (ns < 96 * 12) {
                const int nc = ns / 12, nk = ns - nc * 12;
                const size_t ga = ((size_t)(row0 + ar) * DM + nk * 64 + akq * 8) >> 2;
                pa[0] = x4[ga]; pa[1] = x4[ga + 1];
                const size_t gb = ((size_t)(nc * 128 + bf_) * DM + nk * 64 + bkh * 32) >> 2;
                #pragma unroll
                for (int i = 0; i < 8; ++i) pw[i] = we4[gb + i];
            }
            #pragma unroll
            for (int kb = 0; kb < 2; ++kb) {
                const int ko = kb * 32 + g * 8;
                U8 a0, a1, b0, b1;
                a0.q = *(const uint4*)&Au[ ln       * 72 + ko];
                a1.q = *(const uint4*)&Au[(16 + ln) * 72 + ko];
                b0.q = *(const uint4*)&Bu[(w * 32      + ln) * 72 + ko];
                b1.q = *(const uint4*)&Bu[(w * 32 + 16 + ln) * 72 + ko];
                acc[0][0] = __builtin_amdgcn_mfma_f32_16x16x32_bf16(a0.v, b0.v, acc[0][0], 0, 0, 0);
                acc[0][1] = __builtin_amdgcn_mfma_f32_16x16x32_bf16(a0.v, b1.v, acc[0][1], 0, 0, 0);
                acc[1][0] = __builtin_amdgcn_mfma_f32_16x16x32_bf16(a1.v, b0.v, acc[1][0], 0, 0, 0);
                acc[1][1] = __builtin_amdgcn_mfma_f32_16x16x32_bf16(a1.v, b1.v, acc[1][1], 0, 0, 0);
            }
        }

        // z~ = acc + b_enc.  D layout: n = lane&15, m = (lane>>4)*4 + reg.
        const float be0 = be[f0 + w * 32 + ln];
        const float be1 = be[f0 + w * 32 + 16 + ln];
        float vals[16]; int rowa[16], feata[16];
        #pragma unroll
        for (int p = 0; p < 16; ++p) {
            const int q = p >> 2, r = p & 3;
            vals[p]  = acc[q >> 1][q & 1][r] + ((q & 1) ? be1 : be0);
            rowa[p]  = (q >> 1) * 16 + g * 4 + r;
            feata[p] = f0 + w * 32 + (q & 1) * 16 + ln;
        }

        // streaming push -> per-row queue -> serial two-level replace-min merge
        unsigned pend = 0xFFFFu;
        while (true) {
            #pragma unroll
            for (int p = 0; p < 16; ++p) {
                if (pend & (1u << p)) {
                    const int rr = rowa[p];
                    if (vals[p] > cminA[rr]) {
                        const int pos = atomicAdd(&qn[rr], 1);
                        if (pos < QCAP) {
                            qv[rr * QS + pos] = vals[p];
                            qi[rr * QS + pos] = feata[p];
                            pend &= ~(1u << p);
                        }
                    } else pend &= ~(1u << p);
                }
            }
            const int more = __syncthreads_count(pend != 0);
            if (t < RPB) {
                int n = qn[t]; if (n > QCAP) n = QCAP;
                float cm = cminA[t]; int cp = cposA[t];
                for (int j = 0; j < n; ++j) {
                    const float v = qv[t * QS + j];
                    if (v > cm) {
                        hv[t * HS + cp] = v; hidx[t * HS + cp] = (u16)qi[t * QS + j];
                        const int grp = cp >> 3;
                        float m = hv[t * HS + grp * 8];
                        #pragma unroll
                        for (int i2 = 1; i2 < 8; ++i2)
                            m = fminf(m, hv[t * HS + grp * 8 + i2]);
                        gmin[t * GS + grp] = m;
                        float bm = gmin[t * GS]; int bg = 0;
                        #pragma unroll
                        for (int i2 = 1; i2 < 12; ++i2) {
                            const float gm2 = gmin[t * GS + i2];
                            if (gm2 < bm) { bm = gm2; bg = i2; }
                        }
                        int bp = bg * 8; float bv = hv[t * HS + bg * 8];
                        #pragma unroll
                        for (int i2 = 1; i2 < 8; ++i2) {
                            const float hv2 = hv[t * HS + bg * 8 + i2];
                            if (hv2 < bv) { bv = hv2; bp = bg * 8 + i2; }
                        }
                        cm = bv; cp = bp;
                    }
                }
                qn[t] = 0; cminA[t] = cm; cposA[t] = cp;
            }
            __syncthreads();
            if (more == 0) break;
        }
    }

    for (int e = t; e < RPB * KH; e += 256) {
        const int r = e / KH, k = e - r * KH;
        candv[(size_t)(row0 + r) * KH + k] = hv[r * HS + k];
        candi[(size_t)(row0 + r) * KH + k] = (int)hidx[r * HS + k];
    }
}

// ---------------------------------------------------------------------------
// Rescore the 96 candidates per row in EXACT f64 (reproduces R5's passing
// numerics: fp32 products exact in f64, ~1e-13 sum error << 1e-6 min gaps),
// rank with stable tie-break (z desc, idx asc), emit top-64.
// One block (256 thr = 4 waves) per row; wave handles 24 candidates.
// ---------------------------------------------------------------------------
__global__ __launch_bounds__(256) void rescore(
    const float* __restrict__ x, const float* __restrict__ pb,
    const float* __restrict__ we, const float* __restrict__ be,
    const float* __restrict__ candv, const int* __restrict__ candi,
    float* __restrict__ ov, int* __restrict__ oi)
{
    __shared__ double xs[DM];       // centered row (exact)
    __shared__ double zex[KH];
    __shared__ int    cidx[KH];
    const int row = blockIdx.x, t = threadIdx.x;
    const int wv = t >> 6, l = t & 63;

    for (int k = t; k < DM; k += 256)
        xs[k] = (double)x[(size_t)row * DM + k] - (double)pb[k];
    if (t < KH) {
        int ix = candi[(size_t)row * KH + t];
        cidx[t] = (ix < 0) ? 0 : (ix >= NF ? NF - 1 : ix);
    }
    __syncthreads();

    #pragma unroll 1
    for (int c = wv; c < KH; c += 4) {
        const int fi = cidx[c];
        const float* wr = we + (size_t)fi * DM;
        double s = 0.0;
        #pragma unroll
        for (int i = 0; i < 12; ++i)
            s += xs[l + 64 * i] * (double)wr[l + 64 * i];
        #pragma unroll
        for (int off = 32; off >= 1; off >>= 1)
            s += __shfl_down(s, off);
        if (l == 0) zex[c] = s + (double)be[fi];
    }
    __syncthreads();

    if (t < KH) {
        const double zc = zex[t]; const int ic = cidx[t];
        int rank = 0;
        for (int j = 0; j < KH; ++j) {
            const double zj = zex[j];
            rank += (zj > zc) || (zj == zc && cidx[j] < ic);
        }
        if (rank < K_TOP) {
            ov[(size_t)row * K_TOP + rank] = (float)zc;
            oi[(size_t)row * K_TOP + rank] = ic;
        }
    }
}

// ---------------------------------------------------------------------------
// W_dec [768, 12288] -> W_decT [12288, 768] fp32, 64x64 LDS tiles
// ---------------------------------------------------------------------------
__global__ __launch_bounds__(256) void transpose_wdec(
    const float* __restrict__ wd, float* __restrict__ wdt)
{
    __shared__ float tile[64 * 65];
    const int t = threadIdx.x;
    const int bd = blockIdx.x % 12;
    const int bf = blockIdx.x / 12;
    const int d0 = bd * 64, f0 = bf * 64;
    #pragma unroll
    for (int i = 0; i < 16; ++i) {
        const int idx = t + 256 * i;
        const int dr = idx >> 6, fc = idx & 63;
        tile[dr * 65 + fc] = wd[(size_t)(d0 + dr) * NF + f0 + fc];
    }
    __syncthreads();
    #pragma unroll
    for (int i = 0; i < 16; ++i) {
        const int idx = t + 256 * i;
        const int fr = idx >> 6, dc = idx & 63;
        wdt[(size_t)(f0 + fr) * DM + d0 + dc] = tile[dc * 65 + fr];
    }
}

// ---------------------------------------------------------------------------
// Decode: one block per row. Zeros the sparse row, scatters relu(topk),
// computes x_hat. Covers entire output (robust to 0xAA poisoning).
// ---------------------------------------------------------------------------
__global__ __launch_bounds__(256) void decode_scatter(
    const float* __restrict__ ov, const int* __restrict__ oi,
    const float* __restrict__ wdt, int use_wdt,
    const float* __restrict__ wd, const float* __restrict__ pb,
    float* __restrict__ out)
{
    const int row = blockIdx.x, t = threadIdx.x;
    __shared__ float sv[K_TOP];
    __shared__ int   si[K_TOP];
    if (t < K_TOP) {
        float v = ov[(size_t)row * K_TOP + t];
        v = v > 0.f ? v : 0.f;
        int ix = oi[(size_t)row * K_TOP + t];
        ix = ix < 0 ? 0 : (ix >= NF ? NF - 1 : ix);
        sv[t] = v; si[t] = ix;
    }
    float* srow = out + (size_t)BATCH * DM + (size_t)row * NF;
    {   // zero sparse row with float4 stores
        float4* z4 = (float4*)srow;
        const float4 zz = {0.f, 0.f, 0.f, 0.f};
        #pragma unroll
        for (int i = 0; i < 12; ++i) z4[t + 256 * i] = zz;
    }
    __syncthreads();
    if (t < K_TOP) srow[si[t]] = sv[t];
    float a0 = 0.f, a1 = 0.f, a2 = 0.f;
    for (int k = 0; k < K_TOP; ++k) {
        const float v = sv[k];
        if (v <= 0.f) continue;                        // wave-uniform
        if (use_wdt) {
            const float* wr = wdt + (size_t)si[k] * DM;
            a0 += v * wr[t]; a1 += v * wr[t + 256]; a2 += v * wr[t + 512];
        } else {
            a0 += v * wd[(size_t)(t)       * NF + si[k]];
            a1 += v * wd[(size_t)(t + 256) * NF + si[k]];
            a2 += v * wd[(size_t)(t + 512) * NF + si[k]];
        }
    }
    out[(size_t)row * DM + t]       = a0 + pb[t];
    out[(size_t)row * DM + t + 256] = a1 + pb[t + 256];
    out[(size_t)row * DM + t + 512] = a2 + pb[t + 512];
}

extern "C" void kernel_launch(void* const* d_in, const int* in_sizes, int n_in,
                              void* d_out, int out_size, void* d_ws, size_t ws_size,
                              hipStream_t stream) {
    const float* x  = (const float*)d_in[0];
    const float* pb = (const float*)d_in[1];
    const float* we = (const float*)d_in[2];
    const float* be = (const float*)d_in[3];
    const float* wd = (const float*)d_in[4];
    float* out = (float*)d_out;

    // ws: ov 2MB | oi 2MB | candv 3.1MB | candi 3.1MB | wdt 37.75MB (optional)
    const size_t OV = 0;
    const size_t OI = OV + (size_t)BATCH * K_TOP * 4;
    const size_t CV = OI + (size_t)BATCH * K_TOP * 4;
    const size_t CI = CV + (size_t)BATCH * KH * 4;
    const size_t WT = CI + (size_t)BATCH * KH * 4;
    const size_t need = WT + (size_t)NF * DM * 4;
    float* ov    = (float*)((char*)d_ws + OV);
    int*   oi    = (int*)((char*)d_ws + OI);
    float* candv = (float*)((char*)d_ws + CV);
    int*   candi = (int*)((char*)d_ws + CI);
    float* wdt   = (float*)((char*)d_ws + WT);
    const int use_wdt = (ws_size >= need) ? 1 : 0;

    if (use_wdt)
        hipLaunchKernelGGL(transpose_wdec, dim3(2304), dim3(256), 0, stream, wd, wdt);
    hipLaunchKernelGGL(encode_topk, dim3(256), dim3(256), 0, stream,
                       x, pb, we, be, candv, candi);
    hipLaunchKernelGGL(rescore, dim3(BATCH), dim3(256), 0, stream,
                       x, pb, we, be, candv, candi, ov, oi);
    hipLaunchKernelGGL(decode_scatter, dim3(BATCH), dim3(256), 0, stream,
                       ov, oi, wdt, use_wdt, wd, pb, out);
}